// Round 5
// baseline (366.143 us; speedup 1.0000x reference)
//
#include <hip/hip_runtime.h>
#include <hip/hip_bf16.h>
#include <cmath>

#define NT    4096            // B*T tokens
#define CDIM  768
#define HDIM  3072
#define NEXP  8
#define CAP   1280            // fixed slot capacity per expert (>=9 sigma headroom)

typedef __bf16 bf16_t;
typedef __bf16 bf16x8 __attribute__((ext_vector_type(8)));
typedef float  f32x4  __attribute__((ext_vector_type(4)));

// async global->LDS, 16B per lane; LDS dest = wave-uniform base + lane*16
__device__ __forceinline__ void glds16(const void* g, void* l) {
    __builtin_amdgcn_global_load_lds(
        (const __attribute__((address_space(1))) void*)g,
        (__attribute__((address_space(3))) void*)l, 16, 0, 0);
}

// ---------- W fp32 (E,R,CC) -> bf16 transposed (E,CC,R), 64x64 tiles ----------
template<int R, int CC>
__global__ __launch_bounds__(256)
void transpose_convert_kernel(const float* __restrict__ in, bf16_t* __restrict__ out) {
    __shared__ float tile[64][68];
    int e = blockIdx.z;
    int c0 = blockIdx.x * 64, r0 = blockIdx.y * 64;
    const float* src = in + (size_t)e * R * CC;
    bf16_t* dst = out + (size_t)e * R * CC;
    int t = threadIdx.x;
    int c4 = (t & 15) * 4, rr = t >> 4;
    #pragma unroll
    for (int i = 0; i < 4; i++) {
        int r = rr + i * 16;
        float4 v = *reinterpret_cast<const float4*>(&src[(size_t)(r0 + r) * CC + c0 + c4]);
        tile[r][c4 + 0] = v.x; tile[r][c4 + 1] = v.y;
        tile[r][c4 + 2] = v.z; tile[r][c4 + 3] = v.w;
    }
    __syncthreads();
    #pragma unroll
    for (int i = 0; i < 4; i++) {
        int cc = rr + i * 16;
        int r4 = (t & 15) * 4;
        union { bf16_t h[4]; uint2 u; } un;
        un.h[0] = (bf16_t)tile[r4 + 0][cc]; un.h[1] = (bf16_t)tile[r4 + 1][cc];
        un.h[2] = (bf16_t)tile[r4 + 2][cc]; un.h[3] = (bf16_t)tile[r4 + 3][cc];
        *reinterpret_cast<uint2*>(&dst[(size_t)(c0 + cc) * R + r0 + r4]) = un.u;
    }
}

// ---------- router: fused x->bf16 + top-2 + hierarchical slot assignment ------
__global__ __launch_bounds__(512)
void router_kernel(const float* __restrict__ x, const float* __restrict__ wg,
                   bf16_t* __restrict__ xb,
                   int* __restrict__ counts, int* __restrict__ tmap,
                   float* __restrict__ gmap, int* __restrict__ smap) {
    __shared__ int lcnt[NEXP];
    __shared__ int gbase[NEXP];
    int tid = threadIdx.x, lane = tid & 63, wid = tid >> 6;
    if (tid < NEXP) lcnt[tid] = 0;
    __syncthreads();

    int ti0[4], ti1[4], tr0[4], tr1[4];
    float tg0[4], tg1[4];

    #pragma unroll
    for (int k = 0; k < 4; k++) {
        int t = blockIdx.x * 32 + wid * 4 + k;
        const float* xr = x + (size_t)t * CDIM;
        float acc[NEXP];
        #pragma unroll
        for (int e = 0; e < NEXP; e++) acc[e] = 0.f;
        #pragma unroll
        for (int i = 0; i < CDIM / 256; i++) {     // 3 float4 per lane
            int c = (i * 64 + lane) * 4;
            float4 v = *reinterpret_cast<const float4*>(xr + c);
            union { bf16_t h[4]; uint2 u; } un;
            un.h[0] = (bf16_t)v.x; un.h[1] = (bf16_t)v.y;
            un.h[2] = (bf16_t)v.z; un.h[3] = (bf16_t)v.w;
            *reinterpret_cast<uint2*>(xb + (size_t)t * CDIM + c) = un.u;
            float vv[4] = {v.x, v.y, v.z, v.w};
            #pragma unroll
            for (int j = 0; j < 4; j++)
                #pragma unroll
                for (int e = 0; e < NEXP; e++)
                    acc[e] += vv[j] * wg[(c + j) * NEXP + e];
        }
        #pragma unroll
        for (int e = 0; e < NEXP; e++) {
            #pragma unroll
            for (int off = 32; off > 0; off >>= 1)
                acc[e] += __shfl_xor(acc[e], off, 64);
        }
        if (lane == 0) {
            float mx = acc[0];
            #pragma unroll
            for (int e = 1; e < NEXP; e++) mx = fmaxf(mx, acc[e]);
            float p[NEXP], s = 0.f;
            #pragma unroll
            for (int e = 0; e < NEXP; e++) { p[e] = expf(acc[e] - mx); s += p[e]; }
            float inv = 1.f / s;
            int i0 = 0;
            #pragma unroll
            for (int e = 1; e < NEXP; e++) if (p[e] > p[i0]) i0 = e;  // ties -> lower idx
            int i1 = (i0 == 0) ? 1 : 0;
            #pragma unroll
            for (int e = 0; e < NEXP; e++) if (e != i0 && p[e] > p[i1]) i1 = e;
            ti0[k] = i0; ti1[k] = i1;
            tg0[k] = p[i0] * inv; tg1[k] = p[i1] * inv;
            tr0[k] = atomicAdd(&lcnt[i0], 1);
            tr1[k] = atomicAdd(&lcnt[i1], 1);
        }
    }
    __syncthreads();
    if (tid < NEXP) gbase[tid] = atomicAdd(&counts[tid], lcnt[tid]);
    __syncthreads();
    if (lane == 0) {
        #pragma unroll
        for (int k = 0; k < 4; k++) {
            int t = blockIdx.x * 32 + wid * 4 + k;
            int c0 = gbase[ti0[k]] + tr0[k]; if (c0 >= CAP) c0 = CAP - 1;
            int c1 = gbase[ti1[k]] + tr1[k]; if (c1 >= CAP) c1 = CAP - 1;
            int s0 = ti0[k] * CAP + c0, s1 = ti1[k] * CAP + c1;
            tmap[s0] = t; gmap[s0] = tg0[k]; smap[t * 2]     = s0;
            tmap[s1] = t; gmap[s1] = tg1[k]; smap[t * 2 + 1] = s1;
        }
    }
}

// ---------- GEMM1: 128x128, BK=32, 4-buf depth-2 pipeline, counted vmcnt ----
// h[pos][n] = relu(bf16(X[tmap[pos]]) @ W1t[e] + b1[e])   (K=768, N=3072)
// Buffer algebra (B=4 bufs, depth D=2): stage(t) writes buf (t+2)%4, last
// read at iter t-2; that read completed before its wave issued MFMAs, which
// precede barrier(t-1) < stage(t). RAW: compute(t) reads buf t%4, next
// overwritten by stage(t+2), issued after barrier(t+1) > compute(t) reads.
// One s_barrier per step; per-wave vmcnt(8) = 2 steps x 4 glds16 in flight.
__global__ __launch_bounds__(256)
void moe_gemm1_kernel(const bf16_t* __restrict__ xb, const bf16_t* __restrict__ w1t,
                      const float* __restrict__ b1, const int* __restrict__ counts,
                      const int* __restrict__ tmap, bf16_t* __restrict__ hws) {
    int h = blockIdx.x;
    int e = h & 7;                             // expert <-> XCD partition
    int local = h >> 3;
    int mt = local / (HDIM / 128);
    int nt = local - mt * (HDIM / 128);
    int cnt = counts[e]; if (cnt > CAP) cnt = CAP;
    if (mt * 128 >= cnt) return;
    int m0 = e * CAP + mt * 128;
    int rend = e * CAP + cnt;
    int n0 = nt * 128;

    __shared__ __attribute__((aligned(16))) bf16_t As[4][128 * 32];   // 4 x 8KB
    __shared__ __attribute__((aligned(16))) bf16_t Bs[4][128 * 32];   // 4 x 8KB

    int tid = threadIdx.x, lane = tid & 63, wid = tid >> 6;
    const bf16_t* aP[2];
    const bf16_t* bP[2];
    int reg[2];
    #pragma unroll
    for (int it = 0; it < 2; it++) {
        int region = wid * 2 + it;             // 8 regions x 16 rows
        int row = region * 16 + (lane >> 2);
        int kk = (lane & 3) * 8;
        int pos = m0 + row;
        if (pos > rend - 1) pos = rend - 1;    // clamp, masked in epilogue
        aP[it] = xb + (size_t)tmap[pos] * CDIM + kk;
        bP[it] = w1t + ((size_t)e * HDIM + n0 + row) * CDIM + kk;
        reg[it] = region * 512;                // 1KB wave-uniform LDS region
    }

    // prologue: stage steps 0,1 into bufs 0,1
    #pragma unroll
    for (int it = 0; it < 2; it++) {
        glds16(aP[it],      &As[0][reg[it]]);
        glds16(bP[it],      &Bs[0][reg[it]]);
    }
    #pragma unroll
    for (int it = 0; it < 2; it++) {
        glds16(aP[it] + 32, &As[1][reg[it]]);
        glds16(bP[it] + 32, &Bs[1][reg[it]]);
    }

    int wm = (wid >> 1) * 64, wn = (wid & 1) * 64;
    int q = lane >> 4, mr = lane & 15;

    f32x4 acc[4][4];
    #pragma unroll
    for (int i = 0; i < 4; i++)
        #pragma unroll
        for (int j = 0; j < 4; j++)
            acc[i][j] = (f32x4){0.f, 0.f, 0.f, 0.f};

    const int NSTEP = CDIM / 32;   // 24
    int rb = 0;
    for (int t = 0; t < NSTEP; t++) {
        int sb = rb + 2; if (sb >= 4) sb -= 4;
        if (t + 2 < NSTEP) {
            int ko = (t + 2) * 32;
            #pragma unroll
            for (int it = 0; it < 2; it++) {
                glds16(aP[it] + ko, &As[sb][reg[it]]);
                glds16(bP[it] + ko, &Bs[sb][reg[it]]);
            }
            asm volatile("s_waitcnt vmcnt(8)" ::: "memory");
        } else if (t + 2 == NSTEP) {
            asm volatile("s_waitcnt vmcnt(4)" ::: "memory");
        } else {
            asm volatile("s_waitcnt vmcnt(0)" ::: "memory");
        }
        __builtin_amdgcn_s_barrier();
        __builtin_amdgcn_sched_barrier(0);
        const bf16_t* Ab = &As[rb][0];
        const bf16_t* Bb = &Bs[rb][0];
        bf16x8 af[4], bfr[4];
        #pragma unroll
        for (int ti = 0; ti < 4; ti++)
            af[ti] = *reinterpret_cast<const bf16x8*>(&Ab[(wm + ti * 16 + mr) * 32 + q * 8]);
        #pragma unroll
        for (int tj = 0; tj < 4; tj++)
            bfr[tj] = *reinterpret_cast<const bf16x8*>(&Bb[(wn + tj * 16 + mr) * 32 + q * 8]);
        #pragma unroll
        for (int ti = 0; ti < 4; ti++)
            #pragma unroll
            for (int tj = 0; tj < 4; tj++)
                acc[ti][tj] = __builtin_amdgcn_mfma_f32_16x16x32_bf16(af[ti], bfr[tj], acc[ti][tj], 0, 0, 0);
        rb = rb + 1; if (rb >= 4) rb -= 4;
    }
    __builtin_amdgcn_sched_barrier(0);

    const float* be = b1 + (size_t)e * HDIM + n0;
    #pragma unroll
    for (int ti = 0; ti < 4; ti++) {
        #pragma unroll
        for (int r = 0; r < 4; r++) {
            int pos = m0 + wm + ti * 16 + q * 4 + r;
            if (pos < rend) {
                bf16_t* hrow = hws + (size_t)pos * HDIM + n0;
                #pragma unroll
                for (int tj = 0; tj < 4; tj++) {
                    float v = acc[ti][tj][r] + be[wn + tj * 16 + mr];
                    hrow[wn + tj * 16 + mr] = (bf16_t)fmaxf(v, 0.f);
                }
            }
        }
    }
}

// ---------- GEMM2: 128x128, BK=32, 4-buf depth-2 pipeline, counted vmcnt ----
// yws[pos][c] = gmap[pos] * (h[pos] @ W2t[e] + b2[e])   (K=3072, N=768)
__global__ __launch_bounds__(256)
void moe_gemm2_kernel(const bf16_t* __restrict__ hws, const bf16_t* __restrict__ w2t,
                      const float* __restrict__ b2, const int* __restrict__ counts,
                      const float* __restrict__ gmap, float* __restrict__ yws) {
    int h = blockIdx.x;
    int e = h & 7;
    int local = h >> 3;
    int mt = local / (CDIM / 128);
    int nt = local - mt * (CDIM / 128);
    int cnt = counts[e]; if (cnt > CAP) cnt = CAP;
    if (mt * 128 >= cnt) return;
    int m0 = e * CAP + mt * 128;
    int rend = e * CAP + cnt;
    int n0 = nt * 128;

    __shared__ __attribute__((aligned(16))) bf16_t As[4][128 * 32];   // 4 x 8KB
    __shared__ __attribute__((aligned(16))) bf16_t Bs[4][128 * 32];   // 4 x 8KB

    int tid = threadIdx.x, lane = tid & 63, wid = tid >> 6;
    const bf16_t* aP[2];
    const bf16_t* bP[2];
    int reg[2];
    #pragma unroll
    for (int it = 0; it < 2; it++) {
        int region = wid * 2 + it;             // 8 regions x 16 rows
        int row = region * 16 + (lane >> 2);
        int kk = (lane & 3) * 8;
        int pos = m0 + row;
        if (pos > rend - 1) pos = rend - 1;    // clamp, masked in epilogue
        aP[it] = hws + (size_t)pos * HDIM + kk;           // hws rows slot-direct
        bP[it] = w2t + ((size_t)e * CDIM + n0 + row) * HDIM + kk;
        reg[it] = region * 512;                // 1KB wave-uniform LDS region
    }

    // prologue: stage steps 0,1 into bufs 0,1
    #pragma unroll
    for (int it = 0; it < 2; it++) {
        glds16(aP[it],      &As[0][reg[it]]);
        glds16(bP[it],      &Bs[0][reg[it]]);
    }
    #pragma unroll
    for (int it = 0; it < 2; it++) {
        glds16(aP[it] + 32, &As[1][reg[it]]);
        glds16(bP[it] + 32, &Bs[1][reg[it]]);
    }

    int wm = (wid >> 1) * 64, wn = (wid & 1) * 64;
    int q = lane >> 4, mr = lane & 15;

    f32x4 acc[4][4];
    #pragma unroll
    for (int i = 0; i < 4; i++)
        #pragma unroll
        for (int j = 0; j < 4; j++)
            acc[i][j] = (f32x4){0.f, 0.f, 0.f, 0.f};

    const int NSTEP = HDIM / 32;   // 96
    int rb = 0;
    for (int t = 0; t < NSTEP; t++) {
        int sb = rb + 2; if (sb >= 4) sb -= 4;
        if (t + 2 < NSTEP) {
            int ko = (t + 2) * 32;
            #pragma unroll
            for (int it = 0; it < 2; it++) {
                glds16(aP[it] + ko, &As[sb][reg[it]]);
                glds16(bP[it] + ko, &Bs[sb][reg[it]]);
            }
            asm volatile("s_waitcnt vmcnt(8)" ::: "memory");
        } else if (t + 2 == NSTEP) {
            asm volatile("s_waitcnt vmcnt(4)" ::: "memory");
        } else {
            asm volatile("s_waitcnt vmcnt(0)" ::: "memory");
        }
        __builtin_amdgcn_s_barrier();
        __builtin_amdgcn_sched_barrier(0);
        const bf16_t* Ab = &As[rb][0];
        const bf16_t* Bb = &Bs[rb][0];
        bf16x8 af[4], bfr[4];
        #pragma unroll
        for (int ti = 0; ti < 4; ti++)
            af[ti] = *reinterpret_cast<const bf16x8*>(&Ab[(wm + ti * 16 + mr) * 32 + q * 8]);
        #pragma unroll
        for (int tj = 0; tj < 4; tj++)
            bfr[tj] = *reinterpret_cast<const bf16x8*>(&Bb[(wn + tj * 16 + mr) * 32 + q * 8]);
        #pragma unroll
        for (int ti = 0; ti < 4; ti++)
            #pragma unroll
            for (int tj = 0; tj < 4; tj++)
                acc[ti][tj] = __builtin_amdgcn_mfma_f32_16x16x32_bf16(af[ti], bfr[tj], acc[ti][tj], 0, 0, 0);
        rb = rb + 1; if (rb >= 4) rb -= 4;
    }
    __builtin_amdgcn_sched_barrier(0);

    const float* be = b2 + (size_t)e * CDIM + n0;
    #pragma unroll
    for (int ti = 0; ti < 4; ti++) {
        #pragma unroll
        for (int r = 0; r < 4; r++) {
            int pos = m0 + wm + ti * 16 + q * 4 + r;
            if (pos < rend) {
                float g = gmap[pos];
                float* yrow = yws + (size_t)pos * CDIM + n0;
                #pragma unroll
                for (int tj = 0; tj < 4; tj++) {
                    float v = acc[ti][tj][r] + be[wn + tj * 16 + mr];
                    yrow[wn + tj * 16 + mr] = g * v;
                }
            }
        }
    }
}

// ---------- combine: out[t] = yws[slot0(t)] + yws[slot1(t)] ----------
__global__ __launch_bounds__(256)
void combine_kernel(const float* __restrict__ yws, const int* __restrict__ smap,
                    float* __restrict__ out) {
    int idx = blockIdx.x * 256 + threadIdx.x;  // one float4 per thread
    int t = idx / (CDIM / 4);
    int c = (idx - t * (CDIM / 4)) * 4;
    int s0 = smap[t * 2], s1 = smap[t * 2 + 1];
    float4 a = *reinterpret_cast<const float4*>(yws + (size_t)s0 * CDIM + c);
    float4 b = *reinterpret_cast<const float4*>(yws + (size_t)s1 * CDIM + c);
    float4 o = {a.x + b.x, a.y + b.y, a.z + b.z, a.w + b.w};
    *reinterpret_cast<float4*>(out + (size_t)t * CDIM + c) = o;
}

extern "C" void kernel_launch(void* const* d_in, const int* in_sizes, int n_in,
                              void* d_out, int out_size, void* d_ws, size_t ws_size,
                              hipStream_t stream) {
    const float* x  = (const float*)d_in[0];
    const float* wg = (const float*)d_in[1];
    const float* w1 = (const float*)d_in[2];
    const float* b1 = (const float*)d_in[3];
    const float* w2 = (const float*)d_in[4];
    const float* b2 = (const float*)d_in[5];
    float* out = (float*)d_out;

    char* w = (char*)d_ws;
    size_t off = 0;
    bf16_t* xb  = (bf16_t*)(w + off); off += (size_t)NT * CDIM * 2;             // 6.3 MB
    bf16_t* w1t = (bf16_t*)(w + off); off += (size_t)NEXP * CDIM * HDIM * 2;    // 37.7 MB
    bf16_t* w2t = (bf16_t*)(w + off); off += (size_t)NEXP * CDIM * HDIM * 2;    // 37.7 MB
    bf16_t* hws = (bf16_t*)(w + off); off += (size_t)NEXP * CAP * HDIM * 2;     // 62.9 MB
    float* yws  = (float*)w1t;      // 31.5 MB, aliases w1t (dead after GEMM1)
    int* counts = (int*)(w + off);  off += 64;
    int* tmap   = (int*)(w + off);  off += (size_t)NEXP * CAP * 4;
    int* smap   = (int*)(w + off);  off += (size_t)NT * 2 * 4;
    float* gmap = (float*)(w + off);

    hipMemsetAsync(counts, 0, NEXP * sizeof(int), stream);

    transpose_convert_kernel<CDIM, HDIM>
        <<<dim3(HDIM / 64, CDIM / 64, NEXP), 256, 0, stream>>>(w1, w1t);
    transpose_convert_kernel<HDIM, CDIM>
        <<<dim3(CDIM / 64, HDIM / 64, NEXP), 256, 0, stream>>>(w2, w2t);
    router_kernel<<<NT / 32, 512, 0, stream>>>(x, wg, xb, counts, tmap, gmap, smap);

    moe_gemm1_kernel<<<8 * (CAP / 128) * (HDIM / 128), 256, 0, stream>>>(
        xb, w1t, b1, counts, tmap, hws);
    moe_gemm2_kernel<<<8 * (CAP / 128) * (CDIM / 128), 256, 0, stream>>>(
        hws, w2t, b2, counts, gmap, yws);
    combine_kernel<<<NT * (CDIM / 4) / 256, 256, 0, stream>>>(yws, smap, out);
}

// Round 6
// 357.793 us; speedup vs baseline: 1.0233x; 1.0233x over previous
//
#include <hip/hip_runtime.h>
#include <hip/hip_bf16.h>
#include <cmath>

#define NT    4096            // B*T tokens
#define CDIM  768
#define HDIM  3072
#define NEXP  8
#define CAP   1280            // fixed slot capacity per expert (>=9 sigma headroom)

typedef __bf16 bf16_t;
typedef __bf16 bf16x8 __attribute__((ext_vector_type(8)));
typedef float  f32x4  __attribute__((ext_vector_type(4)));

// async global->LDS, 16B per lane; LDS dest = wave-uniform base + lane*16
__device__ __forceinline__ void glds16(const void* g, void* l) {
    __builtin_amdgcn_global_load_lds(
        (const __attribute__((address_space(1))) void*)g,
        (__attribute__((address_space(3))) void*)l, 16, 0, 0);
}

// ---------- prep: both W transposes in ONE kernel, 16B stores ----------
// z<8: W1 (E,C,H) -> w1t (E,H,C);  z>=8: W2 (E,H,C) -> w2t (E,C,H).
// 64x64 fp32 tile in LDS; writes are uint4 = 8 bf16 along 8 consecutive
// output rows (128B per 8 lanes, fully coalesced).
__global__ __launch_bounds__(256)
void prep_kernel(const float* __restrict__ w1, const float* __restrict__ w2,
                 bf16_t* __restrict__ w1t, bf16_t* __restrict__ w2t) {
    __shared__ float tile[64][68];
    int z = blockIdx.z;
    bool isW1 = z < 8;
    int e = isW1 ? z : z - 8;
    int R  = isW1 ? CDIM : HDIM;
    int CC = isW1 ? HDIM : CDIM;
    const float* src = (isW1 ? w1 : w2) + (size_t)e * CDIM * HDIM;
    bf16_t* dst = (isW1 ? w1t : w2t) + (size_t)e * CDIM * HDIM;
    int ntc = CC / 64;
    int bx = blockIdx.x;
    int c0 = (bx % ntc) * 64, r0 = (bx / ntc) * 64;
    int t = threadIdx.x;
    int c4 = (t & 15) * 4, rr = t >> 4;
    #pragma unroll
    for (int i = 0; i < 4; i++) {
        int r = rr + i * 16;
        float4 v = *reinterpret_cast<const float4*>(&src[(size_t)(r0 + r) * CC + c0 + c4]);
        *reinterpret_cast<float4*>(&tile[r][c4]) = v;
    }
    __syncthreads();
    int r8 = (t & 7) * 8;
    #pragma unroll
    for (int i = 0; i < 2; i++) {
        int cc = (t >> 3) + i * 32;
        union { bf16_t h[8]; uint4 u; } pk;
        #pragma unroll
        for (int s = 0; s < 8; s++) pk.h[s] = (bf16_t)tile[r8 + s][cc];
        *reinterpret_cast<uint4*>(&dst[(size_t)(c0 + cc) * R + r0 + r8]) = pk.u;
    }
}

// ---------- router: fused x->bf16 + top-2 + hierarchical slot assignment ------
// 256 thr = 4 waves x 4 tokens = 16 tokens/block -> 256 blocks (full GPU).
__global__ __launch_bounds__(256)
void router_kernel(const float* __restrict__ x, const float* __restrict__ wg,
                   bf16_t* __restrict__ xb,
                   int* __restrict__ counts, int* __restrict__ tmap,
                   float* __restrict__ gmap, int* __restrict__ smap) {
    __shared__ int lcnt[NEXP];
    __shared__ int gbase[NEXP];
    int tid = threadIdx.x, lane = tid & 63, wid = tid >> 6;
    if (tid < NEXP) lcnt[tid] = 0;
    __syncthreads();

    int ti0[4], ti1[4], tr0[4], tr1[4];
    float tg0[4], tg1[4];

    #pragma unroll
    for (int k = 0; k < 4; k++) {
        int t = blockIdx.x * 16 + wid * 4 + k;
        const float* xr = x + (size_t)t * CDIM;
        float acc[NEXP];
        #pragma unroll
        for (int e = 0; e < NEXP; e++) acc[e] = 0.f;
        #pragma unroll
        for (int i = 0; i < CDIM / 256; i++) {     // 3 float4 per lane
            int c = (i * 64 + lane) * 4;
            float4 v = *reinterpret_cast<const float4*>(xr + c);
            union { bf16_t h[4]; uint2 u; } un;
            un.h[0] = (bf16_t)v.x; un.h[1] = (bf16_t)v.y;
            un.h[2] = (bf16_t)v.z; un.h[3] = (bf16_t)v.w;
            *reinterpret_cast<uint2*>(xb + (size_t)t * CDIM + c) = un.u;
            float vv[4] = {v.x, v.y, v.z, v.w};
            #pragma unroll
            for (int j = 0; j < 4; j++)
                #pragma unroll
                for (int e = 0; e < NEXP; e++)
                    acc[e] += vv[j] * wg[(c + j) * NEXP + e];
        }
        #pragma unroll
        for (int e = 0; e < NEXP; e++) {
            #pragma unroll
            for (int off = 32; off > 0; off >>= 1)
                acc[e] += __shfl_xor(acc[e], off, 64);
        }
        if (lane == 0) {
            float mx = acc[0];
            #pragma unroll
            for (int e = 1; e < NEXP; e++) mx = fmaxf(mx, acc[e]);
            float p[NEXP], s = 0.f;
            #pragma unroll
            for (int e = 0; e < NEXP; e++) { p[e] = expf(acc[e] - mx); s += p[e]; }
            float inv = 1.f / s;
            int i0 = 0;
            #pragma unroll
            for (int e = 1; e < NEXP; e++) if (p[e] > p[i0]) i0 = e;  // ties -> lower idx
            int i1 = (i0 == 0) ? 1 : 0;
            #pragma unroll
            for (int e = 0; e < NEXP; e++) if (e != i0 && p[e] > p[i1]) i1 = e;
            ti0[k] = i0; ti1[k] = i1;
            tg0[k] = p[i0] * inv; tg1[k] = p[i1] * inv;
            tr0[k] = atomicAdd(&lcnt[i0], 1);
            tr1[k] = atomicAdd(&lcnt[i1], 1);
        }
    }
    __syncthreads();
    if (tid < NEXP) gbase[tid] = atomicAdd(&counts[tid], lcnt[tid]);
    __syncthreads();
    if (lane == 0) {
        #pragma unroll
        for (int k = 0; k < 4; k++) {
            int t = blockIdx.x * 16 + wid * 4 + k;
            int c0 = gbase[ti0[k]] + tr0[k]; if (c0 >= CAP) c0 = CAP - 1;
            int c1 = gbase[ti1[k]] + tr1[k]; if (c1 >= CAP) c1 = CAP - 1;
            int s0 = ti0[k] * CAP + c0, s1 = ti1[k] * CAP + c1;
            tmap[s0] = t; gmap[s0] = tg0[k]; smap[t * 2]     = s0;
            tmap[s1] = t; gmap[s1] = tg1[k]; smap[t * 2 + 1] = s1;
        }
    }
}

// ---------- GEMM1: m97-shape 128x128, BK=32, expert<->XCD partition ----------
// h[pos][n] = relu(bf16(X[tmap[pos]]) @ W1t[e] + b1[e])   (K=768, N=3072)
__global__ __launch_bounds__(256)
void moe_gemm1_kernel(const bf16_t* __restrict__ xb, const bf16_t* __restrict__ w1t,
                      const float* __restrict__ b1, const int* __restrict__ counts,
                      const int* __restrict__ tmap, bf16_t* __restrict__ hws) {
    int h = blockIdx.x;
    int e = h & 7;                             // expert <-> XCD partition
    int local = h >> 3;
    int mt = local / (HDIM / 128);
    int nt = local - mt * (HDIM / 128);
    int cnt = counts[e]; if (cnt > CAP) cnt = CAP;
    if (mt * 128 >= cnt) return;
    int m0 = e * CAP + mt * 128;
    int rend = e * CAP + cnt;
    int n0 = nt * 128;

    __shared__ __attribute__((aligned(16))) bf16_t As[128 * 32];   // 8KB
    __shared__ __attribute__((aligned(16))) bf16_t Bs[128 * 32];   // 8KB

    int tid = threadIdx.x, lane = tid & 63, wid = tid >> 6;
    const bf16_t* aP[2];
    const bf16_t* bP[2];
    int reg[2];
    #pragma unroll
    for (int it = 0; it < 2; it++) {
        int region = wid * 2 + it;             // 8 regions x 16 rows
        int row = region * 16 + (lane >> 2);
        int kk = (lane & 3) * 8;
        int pos = m0 + row;
        if (pos > rend - 1) pos = rend - 1;    // clamp, masked in epilogue
        aP[it] = xb + (size_t)tmap[pos] * CDIM + kk;
        bP[it] = w1t + ((size_t)e * HDIM + n0 + row) * CDIM + kk;
        reg[it] = region * 512;                // 1KB wave-uniform LDS region
    }

    int wm = (wid >> 1) * 64, wn = (wid & 1) * 64;
    int q = lane >> 4, mr = lane & 15;

    f32x4 acc[4][4];
    #pragma unroll
    for (int i = 0; i < 4; i++)
        #pragma unroll
        for (int j = 0; j < 4; j++)
            acc[i][j] = (f32x4){0.f, 0.f, 0.f, 0.f};

    for (int k0 = 0; k0 < CDIM; k0 += 32) {
        #pragma unroll
        for (int it = 0; it < 2; it++) {
            glds16(aP[it] + k0, As + reg[it]);
            glds16(bP[it] + k0, Bs + reg[it]);
        }
        __syncthreads();
        bf16x8 af[4], bfr[4];
        #pragma unroll
        for (int ti = 0; ti < 4; ti++)
            af[ti] = *reinterpret_cast<const bf16x8*>(&As[(wm + ti * 16 + mr) * 32 + q * 8]);
        #pragma unroll
        for (int tj = 0; tj < 4; tj++)
            bfr[tj] = *reinterpret_cast<const bf16x8*>(&Bs[(wn + tj * 16 + mr) * 32 + q * 8]);
        #pragma unroll
        for (int ti = 0; ti < 4; ti++)
            #pragma unroll
            for (int tj = 0; tj < 4; tj++)
                acc[ti][tj] = __builtin_amdgcn_mfma_f32_16x16x32_bf16(af[ti], bfr[tj], acc[ti][tj], 0, 0, 0);
        __syncthreads();
    }

    const float* be = b1 + (size_t)e * HDIM + n0;
    #pragma unroll
    for (int ti = 0; ti < 4; ti++) {
        #pragma unroll
        for (int r = 0; r < 4; r++) {
            int pos = m0 + wm + ti * 16 + q * 4 + r;
            if (pos < rend) {
                bf16_t* hrow = hws + (size_t)pos * HDIM + n0;
                #pragma unroll
                for (int tj = 0; tj < 4; tj++) {
                    float v = acc[ti][tj][r] + be[wn + tj * 16 + mr];
                    hrow[wn + tj * 16 + mr] = (bf16_t)fmaxf(v, 0.f);
                }
            }
        }
    }
}

// ---------- GEMM2: m97-shape 128x128, BK=32, expert<->XCD partition ----------
// yws[pos][c] = gmap[pos] * (h[pos] @ W2t[e] + b2[e])   (K=3072, N=768)
__global__ __launch_bounds__(256)
void moe_gemm2_kernel(const bf16_t* __restrict__ hws, const bf16_t* __restrict__ w2t,
                      const float* __restrict__ b2, const int* __restrict__ counts,
                      const float* __restrict__ gmap, float* __restrict__ yws) {
    int h = blockIdx.x;
    int e = h & 7;
    int local = h >> 3;
    int mt = local / (CDIM / 128);
    int nt = local - mt * (CDIM / 128);
    int cnt = counts[e]; if (cnt > CAP) cnt = CAP;
    if (mt * 128 >= cnt) return;
    int m0 = e * CAP + mt * 128;
    int rend = e * CAP + cnt;
    int n0 = nt * 128;

    __shared__ __attribute__((aligned(16))) bf16_t As[128 * 32];   // 8KB
    __shared__ __attribute__((aligned(16))) bf16_t Bs[128 * 32];   // 8KB

    int tid = threadIdx.x, lane = tid & 63, wid = tid >> 6;
    const bf16_t* aP[2];
    const bf16_t* bP[2];
    int reg[2];
    #pragma unroll
    for (int it = 0; it < 2; it++) {
        int region = wid * 2 + it;             // 8 regions x 16 rows
        int row = region * 16 + (lane >> 2);
        int kk = (lane & 3) * 8;
        int pos = m0 + row;
        if (pos > rend - 1) pos = rend - 1;    // clamp, masked in epilogue
        aP[it] = hws + (size_t)pos * HDIM + kk;           // hws rows slot-direct
        bP[it] = w2t + ((size_t)e * CDIM + n0 + row) * HDIM + kk;
        reg[it] = region * 512;                // 1KB wave-uniform LDS region
    }

    int wm = (wid >> 1) * 64, wn = (wid & 1) * 64;
    int q = lane >> 4, mr = lane & 15;

    f32x4 acc[4][4];
    #pragma unroll
    for (int i = 0; i < 4; i++)
        #pragma unroll
        for (int j = 0; j < 4; j++)
            acc[i][j] = (f32x4){0.f, 0.f, 0.f, 0.f};

    for (int k0 = 0; k0 < HDIM; k0 += 32) {
        #pragma unroll
        for (int it = 0; it < 2; it++) {
            glds16(aP[it] + k0, As + reg[it]);
            glds16(bP[it] + k0, Bs + reg[it]);
        }
        __syncthreads();
        bf16x8 af[4], bfr[4];
        #pragma unroll
        for (int ti = 0; ti < 4; ti++)
            af[ti] = *reinterpret_cast<const bf16x8*>(&As[(wm + ti * 16 + mr) * 32 + q * 8]);
        #pragma unroll
        for (int tj = 0; tj < 4; tj++)
            bfr[tj] = *reinterpret_cast<const bf16x8*>(&Bs[(wn + tj * 16 + mr) * 32 + q * 8]);
        #pragma unroll
        for (int ti = 0; ti < 4; ti++)
            #pragma unroll
            for (int tj = 0; tj < 4; tj++)
                acc[ti][tj] = __builtin_amdgcn_mfma_f32_16x16x32_bf16(af[ti], bfr[tj], acc[ti][tj], 0, 0, 0);
        __syncthreads();
    }

    const float* be = b2 + (size_t)e * CDIM + n0;
    #pragma unroll
    for (int ti = 0; ti < 4; ti++) {
        #pragma unroll
        for (int r = 0; r < 4; r++) {
            int pos = m0 + wm + ti * 16 + q * 4 + r;
            if (pos < rend) {
                float g = gmap[pos];
                float* yrow = yws + (size_t)pos * CDIM + n0;
                #pragma unroll
                for (int tj = 0; tj < 4; tj++) {
                    float v = acc[ti][tj][r] + be[wn + tj * 16 + mr];
                    yrow[wn + tj * 16 + mr] = g * v;
                }
            }
        }
    }
}

// ---------- combine: out[t] = yws[slot0(t)] + yws[slot1(t)] ----------
__global__ __launch_bounds__(256)
void combine_kernel(const float* __restrict__ yws, const int* __restrict__ smap,
                    float* __restrict__ out) {
    int idx = blockIdx.x * 256 + threadIdx.x;  // one float4 per thread
    int t = idx / (CDIM / 4);
    int c = (idx - t * (CDIM / 4)) * 4;
    int s0 = smap[t * 2], s1 = smap[t * 2 + 1];
    float4 a = *reinterpret_cast<const float4*>(yws + (size_t)s0 * CDIM + c);
    float4 b = *reinterpret_cast<const float4*>(yws + (size_t)s1 * CDIM + c);
    float4 o = {a.x + b.x, a.y + b.y, a.z + b.z, a.w + b.w};
    *reinterpret_cast<float4*>(out + (size_t)t * CDIM + c) = o;
}

extern "C" void kernel_launch(void* const* d_in, const int* in_sizes, int n_in,
                              void* d_out, int out_size, void* d_ws, size_t ws_size,
                              hipStream_t stream) {
    const float* x  = (const float*)d_in[0];
    const float* wg = (const float*)d_in[1];
    const float* w1 = (const float*)d_in[2];
    const float* b1 = (const float*)d_in[3];
    const float* w2 = (const float*)d_in[4];
    const float* b2 = (const float*)d_in[5];
    float* out = (float*)d_out;

    char* w = (char*)d_ws;
    size_t off = 0;
    bf16_t* xb  = (bf16_t*)(w + off); off += (size_t)NT * CDIM * 2;             // 6.3 MB
    bf16_t* w1t = (bf16_t*)(w + off); off += (size_t)NEXP * CDIM * HDIM * 2;    // 37.7 MB
    bf16_t* w2t = (bf16_t*)(w + off); off += (size_t)NEXP * CDIM * HDIM * 2;    // 37.7 MB
    bf16_t* hws = (bf16_t*)(w + off); off += (size_t)NEXP * CAP * HDIM * 2;     // 62.9 MB
    float* yws  = (float*)w1t;      // 31.5 MB, aliases w1t (dead after GEMM1)
    int* counts = (int*)(w + off);  off += 64;
    int* tmap   = (int*)(w + off);  off += (size_t)NEXP * CAP * 4;
    int* smap   = (int*)(w + off);  off += (size_t)NT * 2 * 4;
    float* gmap = (float*)(w + off);

    hipMemsetAsync(counts, 0, NEXP * sizeof(int), stream);

    router_kernel<<<NT / 16, 256, 0, stream>>>(x, wg, xb, counts, tmap, gmap, smap);
    prep_kernel<<<dim3((CDIM / 64) * (HDIM / 64), 1, 16), 256, 0, stream>>>(
        w1, w2, w1t, w2t);

    moe_gemm1_kernel<<<8 * (CAP / 128) * (HDIM / 128), 256, 0, stream>>>(
        xb, w1t, b1, counts, tmap, hws);
    moe_gemm2_kernel<<<8 * (CAP / 128) * (CDIM / 128), 256, 0, stream>>>(
        hws, w2t, b2, counts, gmap, yws);
    combine_kernel<<<NT * (CDIM / 4) / 256, 256, 0, stream>>>(yws, smap, out);
}

// Round 7
// 345.267 us; speedup vs baseline: 1.0605x; 1.0363x over previous
//
#include <hip/hip_runtime.h>
#include <hip/hip_bf16.h>
#include <cmath>

#define NT    4096            // B*T tokens
#define CDIM  768
#define HDIM  3072
#define NEXP  8
#define CAP   1280            // fixed slot capacity per expert (>=9 sigma headroom)

typedef __bf16 bf16_t;
typedef __bf16 bf16x8 __attribute__((ext_vector_type(8)));
typedef float  f32x4  __attribute__((ext_vector_type(4)));

// async global->LDS, 16B per lane; LDS dest = wave-uniform base + lane*16
__device__ __forceinline__ void glds16(const void* g, void* l) {
    __builtin_amdgcn_global_load_lds(
        (const __attribute__((address_space(1))) void*)g,
        (__attribute__((address_space(3))) void*)l, 16, 0, 0);
}

// ---------- prep: both W transposes in ONE kernel, 16B stores ----------
__global__ __launch_bounds__(256)
void prep_kernel(const float* __restrict__ w1, const float* __restrict__ w2,
                 bf16_t* __restrict__ w1t, bf16_t* __restrict__ w2t) {
    __shared__ float tile[64][68];
    int z = blockIdx.z;
    bool isW1 = z < 8;
    int e = isW1 ? z : z - 8;
    int R  = isW1 ? CDIM : HDIM;
    int CC = isW1 ? HDIM : CDIM;
    const float* src = (isW1 ? w1 : w2) + (size_t)e * CDIM * HDIM;
    bf16_t* dst = (isW1 ? w1t : w2t) + (size_t)e * CDIM * HDIM;
    int ntc = CC / 64;
    int bx = blockIdx.x;
    int c0 = (bx % ntc) * 64, r0 = (bx / ntc) * 64;
    int t = threadIdx.x;
    int c4 = (t & 15) * 4, rr = t >> 4;
    #pragma unroll
    for (int i = 0; i < 4; i++) {
        int r = rr + i * 16;
        float4 v = *reinterpret_cast<const float4*>(&src[(size_t)(r0 + r) * CC + c0 + c4]);
        *reinterpret_cast<float4*>(&tile[r][c4]) = v;
    }
    __syncthreads();
    int r8 = (t & 7) * 8;
    #pragma unroll
    for (int i = 0; i < 2; i++) {
        int cc = (t >> 3) + i * 32;
        union { bf16_t h[8]; uint4 u; } pk;
        #pragma unroll
        for (int s = 0; s < 8; s++) pk.h[s] = (bf16_t)tile[r8 + s][cc];
        *reinterpret_cast<uint4*>(&dst[(size_t)(c0 + cc) * R + r0 + r8]) = pk.u;
    }
}

// ---------- router: fused x->bf16 + top-2 + hierarchical slot assignment ------
__global__ __launch_bounds__(256)
void router_kernel(const float* __restrict__ x, const float* __restrict__ wg,
                   bf16_t* __restrict__ xb,
                   int* __restrict__ counts, int* __restrict__ tmap,
                   float* __restrict__ gmap, int* __restrict__ smap) {
    __shared__ int lcnt[NEXP];
    __shared__ int gbase[NEXP];
    int tid = threadIdx.x, lane = tid & 63, wid = tid >> 6;
    if (tid < NEXP) lcnt[tid] = 0;
    __syncthreads();

    int ti0[4], ti1[4], tr0[4], tr1[4];
    float tg0[4], tg1[4];

    #pragma unroll
    for (int k = 0; k < 4; k++) {
        int t = blockIdx.x * 16 + wid * 4 + k;
        const float* xr = x + (size_t)t * CDIM;
        float acc[NEXP];
        #pragma unroll
        for (int e = 0; e < NEXP; e++) acc[e] = 0.f;
        #pragma unroll
        for (int i = 0; i < CDIM / 256; i++) {     // 3 float4 per lane
            int c = (i * 64 + lane) * 4;
            float4 v = *reinterpret_cast<const float4*>(xr + c);
            union { bf16_t h[4]; uint2 u; } un;
            un.h[0] = (bf16_t)v.x; un.h[1] = (bf16_t)v.y;
            un.h[2] = (bf16_t)v.z; un.h[3] = (bf16_t)v.w;
            *reinterpret_cast<uint2*>(xb + (size_t)t * CDIM + c) = un.u;
            float vv[4] = {v.x, v.y, v.z, v.w};
            #pragma unroll
            for (int j = 0; j < 4; j++)
                #pragma unroll
                for (int e = 0; e < NEXP; e++)
                    acc[e] += vv[j] * wg[(c + j) * NEXP + e];
        }
        #pragma unroll
        for (int e = 0; e < NEXP; e++) {
            #pragma unroll
            for (int off = 32; off > 0; off >>= 1)
                acc[e] += __shfl_xor(acc[e], off, 64);
        }
        if (lane == 0) {
            float mx = acc[0];
            #pragma unroll
            for (int e = 1; e < NEXP; e++) mx = fmaxf(mx, acc[e]);
            float p[NEXP], s = 0.f;
            #pragma unroll
            for (int e = 0; e < NEXP; e++) { p[e] = expf(acc[e] - mx); s += p[e]; }
            float inv = 1.f / s;
            int i0 = 0;
            #pragma unroll
            for (int e = 1; e < NEXP; e++) if (p[e] > p[i0]) i0 = e;  // ties -> lower idx
            int i1 = (i0 == 0) ? 1 : 0;
            #pragma unroll
            for (int e = 0; e < NEXP; e++) if (e != i0 && p[e] > p[i1]) i1 = e;
            ti0[k] = i0; ti1[k] = i1;
            tg0[k] = p[i0] * inv; tg1[k] = p[i1] * inv;
            tr0[k] = atomicAdd(&lcnt[i0], 1);
            tr1[k] = atomicAdd(&lcnt[i1], 1);
        }
    }
    __syncthreads();
    if (tid < NEXP) gbase[tid] = atomicAdd(&counts[tid], lcnt[tid]);
    __syncthreads();
    if (lane == 0) {
        #pragma unroll
        for (int k = 0; k < 4; k++) {
            int t = blockIdx.x * 16 + wid * 4 + k;
            int c0 = gbase[ti0[k]] + tr0[k]; if (c0 >= CAP) c0 = CAP - 1;
            int c1 = gbase[ti1[k]] + tr1[k]; if (c1 >= CAP) c1 = CAP - 1;
            int s0 = ti0[k] * CAP + c0, s1 = ti1[k] * CAP + c1;
            tmap[s0] = t; gmap[s0] = tg0[k]; smap[t * 2]     = s0;
            tmap[s1] = t; gmap[s1] = tg1[k]; smap[t * 2 + 1] = s1;
        }
    }
}

// ---------- GEMM1: 128x128, BK=64, XOR-swizzled LDS (conflict-free) ----------
// h[pos][n] = relu(bf16(X[tmap[pos]]) @ W1t[e] + b1[e])   (K=768, N=3072)
// Swizzle (rule #21, both-sides): LDS dest linear; global SOURCE chunk
// pre-XORed (lane chunk p fetches logical chunk p^(row&7)); ds_read uses
// slot ((ks*4+q)^(mr&7)). Bank count: 8 lanes/slot, 8 dwords/bank = b128
// minimum => conflict-free. Sync structure identical to known-good R1 loop.
__global__ __launch_bounds__(256)
void moe_gemm1_kernel(const bf16_t* __restrict__ xb, const bf16_t* __restrict__ w1t,
                      const float* __restrict__ b1, const int* __restrict__ counts,
                      const int* __restrict__ tmap, bf16_t* __restrict__ hws) {
    int h = blockIdx.x;
    int e = h & 7;                             // expert <-> XCD partition
    int local = h >> 3;
    int mt = local / (HDIM / 128);
    int nt = local - mt * (HDIM / 128);
    int cnt = counts[e]; if (cnt > CAP) cnt = CAP;
    if (mt * 128 >= cnt) return;
    int m0 = e * CAP + mt * 128;
    int rend = e * CAP + cnt;
    int n0 = nt * 128;

    __shared__ __attribute__((aligned(16))) bf16_t As[128 * 64];   // 16KB
    __shared__ __attribute__((aligned(16))) bf16_t Bs[128 * 64];   // 16KB

    int tid = threadIdx.x, lane = tid & 63, wid = tid >> 6;
    int rr = tid >> 3;                 // 0..31 row-in-issue
    int pc = tid & 7;                  // physical 16B chunk
    int lc = pc ^ (rr & 7);            // logical chunk (source pre-swizzle)
    const bf16_t* aPj[4];
    const bf16_t* bPj[4];
    int ldsOff[4];
    #pragma unroll
    for (int j = 0; j < 4; j++) {
        int row = j * 32 + rr;
        int pos = m0 + row;
        if (pos > rend - 1) pos = rend - 1;    // clamp, masked in epilogue
        aPj[j] = xb + (size_t)tmap[pos] * CDIM + lc * 8;
        bPj[j] = w1t + ((size_t)e * HDIM + n0 + row) * CDIM + lc * 8;
        ldsOff[j] = j * 2048 + wid * 512;      // elements; wave-uniform
    }

    int wm = (wid >> 1) * 64, wn = (wid & 1) * 64;
    int q = lane >> 4, mr = lane & 15;
    int sw = mr & 7;

    f32x4 acc[4][4];
    #pragma unroll
    for (int i = 0; i < 4; i++)
        #pragma unroll
        for (int j = 0; j < 4; j++)
            acc[i][j] = (f32x4){0.f, 0.f, 0.f, 0.f};

    for (int k0 = 0; k0 < CDIM; k0 += 64) {
        #pragma unroll
        for (int j = 0; j < 4; j++) {
            glds16(aPj[j] + k0, As + ldsOff[j]);
            glds16(bPj[j] + k0, Bs + ldsOff[j]);
        }
        __syncthreads();
        #pragma unroll
        for (int ks = 0; ks < 2; ks++) {
            int slot = ((ks * 4 + q) ^ sw) * 8;
            bf16x8 af[4], bfr[4];
            #pragma unroll
            for (int ti = 0; ti < 4; ti++)
                af[ti] = *reinterpret_cast<const bf16x8*>(&As[(wm + ti * 16 + mr) * 64 + slot]);
            #pragma unroll
            for (int tj = 0; tj < 4; tj++)
                bfr[tj] = *reinterpret_cast<const bf16x8*>(&Bs[(wn + tj * 16 + mr) * 64 + slot]);
            #pragma unroll
            for (int ti = 0; ti < 4; ti++)
                #pragma unroll
                for (int tj = 0; tj < 4; tj++)
                    acc[ti][tj] = __builtin_amdgcn_mfma_f32_16x16x32_bf16(af[ti], bfr[tj], acc[ti][tj], 0, 0, 0);
        }
        __syncthreads();
    }

    const float* be = b1 + (size_t)e * HDIM + n0;
    #pragma unroll
    for (int ti = 0; ti < 4; ti++) {
        #pragma unroll
        for (int r = 0; r < 4; r++) {
            int pos = m0 + wm + ti * 16 + q * 4 + r;
            if (pos < rend) {
                bf16_t* hrow = hws + (size_t)pos * HDIM + n0;
                #pragma unroll
                for (int tj = 0; tj < 4; tj++) {
                    float v = acc[ti][tj][r] + be[wn + tj * 16 + mr];
                    hrow[wn + tj * 16 + mr] = (bf16_t)fmaxf(v, 0.f);
                }
            }
        }
    }
}

// ---------- GEMM2: 128x128, BK=64, XOR-swizzled LDS (conflict-free) ----------
// yws[pos][c] = gmap[pos] * (h[pos] @ W2t[e] + b2[e])   (K=3072, N=768)
__global__ __launch_bounds__(256)
void moe_gemm2_kernel(const bf16_t* __restrict__ hws, const bf16_t* __restrict__ w2t,
                      const float* __restrict__ b2, const int* __restrict__ counts,
                      const float* __restrict__ gmap, float* __restrict__ yws) {
    int h = blockIdx.x;
    int e = h & 7;
    int local = h >> 3;
    int mt = local / (CDIM / 128);
    int nt = local - mt * (CDIM / 128);
    int cnt = counts[e]; if (cnt > CAP) cnt = CAP;
    if (mt * 128 >= cnt) return;
    int m0 = e * CAP + mt * 128;
    int rend = e * CAP + cnt;
    int n0 = nt * 128;

    __shared__ __attribute__((aligned(16))) bf16_t As[128 * 64];   // 16KB
    __shared__ __attribute__((aligned(16))) bf16_t Bs[128 * 64];   // 16KB

    int tid = threadIdx.x, lane = tid & 63, wid = tid >> 6;
    int rr = tid >> 3;
    int pc = tid & 7;
    int lc = pc ^ (rr & 7);
    const bf16_t* aPj[4];
    const bf16_t* bPj[4];
    int ldsOff[4];
    #pragma unroll
    for (int j = 0; j < 4; j++) {
        int row = j * 32 + rr;
        int pos = m0 + row;
        if (pos > rend - 1) pos = rend - 1;    // clamp, masked in epilogue
        aPj[j] = hws + (size_t)pos * HDIM + lc * 8;       // hws rows slot-direct
        bPj[j] = w2t + ((size_t)e * CDIM + n0 + row) * HDIM + lc * 8;
        ldsOff[j] = j * 2048 + wid * 512;
    }

    int wm = (wid >> 1) * 64, wn = (wid & 1) * 64;
    int q = lane >> 4, mr = lane & 15;
    int sw = mr & 7;

    f32x4 acc[4][4];
    #pragma unroll
    for (int i = 0; i < 4; i++)
        #pragma unroll
        for (int j = 0; j < 4; j++)
            acc[i][j] = (f32x4){0.f, 0.f, 0.f, 0.f};

    for (int k0 = 0; k0 < HDIM; k0 += 64) {
        #pragma unroll
        for (int j = 0; j < 4; j++) {
            glds16(aPj[j] + k0, As + ldsOff[j]);
            glds16(bPj[j] + k0, Bs + ldsOff[j]);
        }
        __syncthreads();
        #pragma unroll
        for (int ks = 0; ks < 2; ks++) {
            int slot = ((ks * 4 + q) ^ sw) * 8;
            bf16x8 af[4], bfr[4];
            #pragma unroll
            for (int ti = 0; ti < 4; ti++)
                af[ti] = *reinterpret_cast<const bf16x8*>(&As[(wm + ti * 16 + mr) * 64 + slot]);
            #pragma unroll
            for (int tj = 0; tj < 4; tj++)
                bfr[tj] = *reinterpret_cast<const bf16x8*>(&Bs[(wn + tj * 16 + mr) * 64 + slot]);
            #pragma unroll
            for (int ti = 0; ti < 4; ti++)
                #pragma unroll
                for (int tj = 0; tj < 4; tj++)
                    acc[ti][tj] = __builtin_amdgcn_mfma_f32_16x16x32_bf16(af[ti], bfr[tj], acc[ti][tj], 0, 0, 0);
        }
        __syncthreads();
    }

    const float* be = b2 + (size_t)e * CDIM + n0;
    #pragma unroll
    for (int ti = 0; ti < 4; ti++) {
        #pragma unroll
        for (int r = 0; r < 4; r++) {
            int pos = m0 + wm + ti * 16 + q * 4 + r;
            if (pos < rend) {
                float g = gmap[pos];
                float* yrow = yws + (size_t)pos * CDIM + n0;
                #pragma unroll
                for (int tj = 0; tj < 4; tj++) {
                    float v = acc[ti][tj][r] + be[wn + tj * 16 + mr];
                    yrow[wn + tj * 16 + mr] = g * v;
                }
            }
        }
    }
}

// ---------- combine: out[t] = yws[slot0(t)] + yws[slot1(t)] ----------
__global__ __launch_bounds__(256)
void combine_kernel(const float* __restrict__ yws, const int* __restrict__ smap,
                    float* __restrict__ out) {
    int idx = blockIdx.x * 256 + threadIdx.x;  // one float4 per thread
    int t = idx / (CDIM / 4);
    int c = (idx - t * (CDIM / 4)) * 4;
    int s0 = smap[t * 2], s1 = smap[t * 2 + 1];
    float4 a = *reinterpret_cast<const float4*>(yws + (size_t)s0 * CDIM + c);
    float4 b = *reinterpret_cast<const float4*>(yws + (size_t)s1 * CDIM + c);
    float4 o = {a.x + b.x, a.y + b.y, a.z + b.z, a.w + b.w};
    *reinterpret_cast<float4*>(out + (size_t)t * CDIM + c) = o;
}

extern "C" void kernel_launch(void* const* d_in, const int* in_sizes, int n_in,
                              void* d_out, int out_size, void* d_ws, size_t ws_size,
                              hipStream_t stream) {
    const float* x  = (const float*)d_in[0];
    const float* wg = (const float*)d_in[1];
    const float* w1 = (const float*)d_in[2];
    const float* b1 = (const float*)d_in[3];
    const float* w2 = (const float*)d_in[4];
    const float* b2 = (const float*)d_in[5];
    float* out = (float*)d_out;

    char* w = (char*)d_ws;
    size_t off = 0;
    bf16_t* xb  = (bf16_t*)(w + off); off += (size_t)NT * CDIM * 2;             // 6.3 MB
    bf16_t* w1t = (bf16_t*)(w + off); off += (size_t)NEXP * CDIM * HDIM * 2;    // 37.7 MB
    bf16_t* w2t = (bf16_t*)(w + off); off += (size_t)NEXP * CDIM * HDIM * 2;    // 37.7 MB
    bf16_t* hws = (bf16_t*)(w + off); off += (size_t)NEXP * CAP * HDIM * 2;     // 62.9 MB
    float* yws  = (float*)w1t;      // 31.5 MB, aliases w1t (dead after GEMM1)
    int* counts = (int*)(w + off);  off += 64;
    int* tmap   = (int*)(w + off);  off += (size_t)NEXP * CAP * 4;
    int* smap   = (int*)(w + off);  off += (size_t)NT * 2 * 4;
    float* gmap = (float*)(w + off);

    hipMemsetAsync(counts, 0, NEXP * sizeof(int), stream);

    router_kernel<<<NT / 16, 256, 0, stream>>>(x, wg, xb, counts, tmap, gmap, smap);
    prep_kernel<<<dim3((CDIM / 64) * (HDIM / 64), 1, 16), 256, 0, stream>>>(
        w1, w2, w1t, w2t);

    moe_gemm1_kernel<<<8 * (CAP / 128) * (HDIM / 128), 256, 0, stream>>>(
        xb, w1t, b1, counts, tmap, hws);
    moe_gemm2_kernel<<<8 * (CAP / 128) * (CDIM / 128), 256, 0, stream>>>(
        hws, w2t, b2, counts, gmap, yws);
    combine_kernel<<<NT * (CDIM / 4) / 256, 256, 0, stream>>>(yws, smap, out);
}